// Round 3
// baseline (231.463 us; speedup 1.0000x reference)
//
#include <hip/hip_runtime.h>
#include <hip/hip_bf16.h>

typedef __attribute__((ext_vector_type(8))) short bf16x8;
typedef __attribute__((ext_vector_type(4))) float f32x4;

__device__ inline short f2bf(float f) {
    __hip_bfloat16 h = __float2bfloat16(f);
    short s;
    __builtin_memcpy(&s, &h, 2);
    return s;
}
__device__ inline float bf2f(short s) {
    unsigned int u = ((unsigned int)(unsigned short)s) << 16;
    float f;
    __builtin_memcpy(&f, &u, 4);
    return f;
}

// async 16B global->LDS; dest must be wave-uniform base + lane*16
__device__ inline void cp16_async(const void* g, void* l) {
    __builtin_amdgcn_global_load_lds(
        (const __attribute__((address_space(1))) void*)g,
        (__attribute__((address_space(3))) void*)l, 16, 0, 0);
}

// ---------------- prep: cast x + transpose-cast all 4 weights ----------------

__global__ void prep_kernel(const float* __restrict__ x, short* __restrict__ Xb,
                            const float* __restrict__ W0, const float* __restrict__ W1,
                            const float* __restrict__ W2, const float* __restrict__ W3,
                            short* __restrict__ W4T) {
    int bid = blockIdx.x;
    if (bid < 8192) {
        int i = bid * 256 + threadIdx.x;
        float4 f = ((const float4*)x)[i];
        union { short s[4]; int2 v; } u;
        u.s[0] = f2bf(f.x); u.s[1] = f2bf(f.y); u.s[2] = f2bf(f.z); u.s[3] = f2bf(f.w);
        ((int2*)Xb)[i] = u.v;
    } else {
        int i = (bid - 8192) * 256 + threadIdx.x;
        int w = i >> 18;
        int r = i & 262143;
        int n = r >> 9, k = r & 511;
        const float* W = (w == 0) ? W0 : (w == 1) ? W1 : (w == 2) ? W2 : W3;
        W4T[i] = f2bf(W[k * 512 + n]);
    }
}

// ========== 256x256 core, 8 waves, BK=64 — round-2-PROVEN 2-phase sync ==========
// Geometry new this round; sync structure identical to the passing round-2 loop:
//   stage(next) -> compute(cur) -> vmcnt(0) -> s_barrier   (one drain per K-tile)
// LDS 128KB static (4 x 32KB dbufs) -> 1 block/CU, 2 waves/SIMD.
// XOR swizzle byte ^= (row&7)<<4 via pre-swizzled global source (dest linear).

__device__ inline void stage256(const short* __restrict__ A, int lda,
                                const short* __restrict__ B, int ldb, int k0,
                                short* sA, short* sB, int tid) {
#pragma unroll
    for (int j = 0; j < 4; ++j) {
        const int L = tid * 16 + j * 8192;            // linear byte in 32KB tile
        const int row = L >> 7;                       // 128B per row (64 bf16)
        const int cb = (L & 127) ^ ((row & 7) << 4);  // inverse-swizzled src col (bytes)
        cp16_async((const char*)(A + (size_t)row * lda + k0) + cb, (char*)sA + L);
        cp16_async((const char*)(B + (size_t)row * ldb + k0) + cb, (char*)sB + L);
    }
}

__device__ inline void compute256(const short* sA, const short* sB, f32x4 acc[8][4],
                                  int aBase, int bBase, int lr, int quad) {
    const int sw = (lr & 7) << 4;                     // swizzle, bytes (row&7 == lr&7)
#pragma unroll
    for (int kk = 0; kk < 2; ++kk) {
        const int cb = (kk * 64 + quad * 16) ^ sw;
        bf16x8 a[8], b[4];
#pragma unroll
        for (int m = 0; m < 8; ++m)
            a[m] = *(const bf16x8*)((const char*)sA + (aBase + m * 16 + lr) * 128 + cb);
#pragma unroll
        for (int n = 0; n < 4; ++n)
            b[n] = *(const bf16x8*)((const char*)sB + (bBase + n * 16 + lr) * 128 + cb);
#pragma unroll
        for (int m = 0; m < 8; ++m)
#pragma unroll
            for (int n = 0; n < 4; ++n)
                acc[m][n] = __builtin_amdgcn_mfma_f32_16x16x32_bf16(a[m], b[n], acc[m][n], 0, 0, 0);
    }
}

__device__ inline void gemm256(const short* __restrict__ A, int lda,
                               const short* __restrict__ B, int ldb, int Kd,
                               f32x4 acc[8][4],
                               short* s0, short* s1, short* s2, short* s3) {
    const int tid = threadIdx.x, lane = tid & 63, wv = tid >> 6;
    const int lr = lane & 15, quad = lane >> 4;
    const int aBase = (wv >> 2) * 128, bBase = (wv & 3) * 64;  // 2x4 waves, 128x64 each
    const int NT = Kd >> 6;
    // prologue: tile 0 -> buf0, full drain (round-2 structure)
    stage256(A, lda, B, ldb, 0, s0, s1, tid);
    __builtin_amdgcn_sched_barrier(0);
    asm volatile("s_waitcnt vmcnt(0)" ::: "memory");
    __builtin_amdgcn_sched_barrier(0);
    __builtin_amdgcn_s_barrier();
    __builtin_amdgcn_sched_barrier(0);
    for (int t = 0; t < NT; ++t) {
        const short* cA = (t & 1) ? s2 : s0;
        const short* cB = (t & 1) ? s3 : s1;
        if (t + 1 < NT)                               // prefetch next tile into other buf
            stage256(A, lda, B, ldb, (t + 1) << 6,
                     (t & 1) ? s0 : s2, (t & 1) ? s1 : s3, tid);
        __builtin_amdgcn_sched_barrier(0);
        compute256(cA, cB, acc, aBase, bBase, lr, quad);
        __builtin_amdgcn_sched_barrier(0);
        asm volatile("s_waitcnt vmcnt(0)" ::: "memory");  // next tile landed under MFMA
        __builtin_amdgcn_sched_barrier(0);
        __builtin_amdgcn_s_barrier();                 // all waves done reading cur buf
        __builtin_amdgcn_sched_barrier(0);
    }
}

// fused QKV projection: C[16384 x 1536] = Xb . W4T[0..1535]^T
// grid 384 = 64 mt x 6 nt; nt 0,1->Q  2,3->K(+Kt scatter)  4,5->Vt scatter only
__global__ __launch_bounds__(512, 2) void proj_qkv(const short* __restrict__ Xb,
                                                   const short* __restrict__ W4T,
                                                   short* __restrict__ Qb, short* __restrict__ Kb,
                                                   short* __restrict__ Vt, short* __restrict__ Kt) {
    __shared__ short sA0[16384], sB0[16384], sA1[16384], sB1[16384];
    const int bid = blockIdx.x;
    const int swz = (bid & 7) * 48 + (bid >> 3);   // bijective XCD swizzle (384 = 8*48)
    const int mt = swz / 6, nt = swz % 6;          // 6 consumers of an X-panel share an XCD
    f32x4 acc[8][4];
#pragma unroll
    for (int m = 0; m < 8; ++m)
#pragma unroll
        for (int n = 0; n < 4; ++n) acc[m][n] = (f32x4){0.f, 0.f, 0.f, 0.f};
    gemm256(Xb + (size_t)mt * 256 * 512, 512, W4T + (size_t)nt * 256 * 512, 512, 512,
            acc, sA0, sB0, sA1, sB1);
    const int lane = threadIdx.x & 63, wv = threadIdx.x >> 6;
    const int wm = wv >> 2, wn = wv & 3;
    const int lr = lane & 15, quad = lane >> 4;
    const int pr = nt >> 1;                        // 0=Q 1=K 2=V
    const int fl = ((nt & 1) << 8) + wn * 64;      // feature col base within projection
    const int tg0 = mt * 256 + wm * 128 + quad * 4;
    if (pr < 2) {                                  // Q or K row-major [t][f]
        short* C = pr ? Kb : Qb;
#pragma unroll
        for (int m = 0; m < 8; ++m)
#pragma unroll
            for (int n = 0; n < 4; ++n) {
                const size_t base = (size_t)(tg0 + m * 16) * 512 + fl + n * 16 + lr;
#pragma unroll
                for (int r = 0; r < 4; ++r)
                    C[base + (size_t)r * 512] = f2bf(acc[m][n][r]);
            }
    }
    if (pr) {                                      // Kt / Vt feature-major [b][f][t]
        short* T = (pr == 1) ? Kt : Vt;
        const int b = tg0 >> 12;                   // 256-row tile never crosses a batch
        const int tl0 = tg0 & 4095;
#pragma unroll
        for (int m = 0; m < 8; ++m)
#pragma unroll
            for (int n = 0; n < 4; ++n) {
                const int f = fl + n * 16 + lr;
                short tmp[4];
#pragma unroll
                for (int r = 0; r < 4; ++r) tmp[r] = f2bf(acc[m][n][r]);
                *(int2*)&T[((size_t)b * 512 + f) * 4096 + tl0 + m * 16] = *(const int2*)tmp;
            }
    }
}

// ========== 128x128 core, 2-phase pipelined (proven round 2) ==========

#define LDS_DECL __shared__ short sm[4][8192]
// sm[0]=A buf0, sm[1]=B buf0, sm[2]=A buf1, sm[3]=B buf1

__device__ inline void stage_tile(const short* __restrict__ A, int lda,
                                  const short* __restrict__ B, int ldb, int k0,
                                  short* sA, short* sB, int tid) {
#pragma unroll
    for (int j = 0; j < 4; ++j) {
        const int L = tid * 16 + j * 4096;            // linear byte in 16KB tile
        const int row = L >> 7;                       // 128B per row (64 bf16)
        const int cb = (L & 127) ^ ((row & 7) << 4);  // inverse-swizzled src col (bytes)
        cp16_async(A + (size_t)row * lda + k0 + (cb >> 1), (char*)sA + L);
        cp16_async(B + (size_t)row * ldb + k0 + (cb >> 1), (char*)sB + L);
    }
}

__device__ inline void compute_tile(const short* sA, const short* sB, f32x4* acc,
                                    int wr, int wc, int lr, int quad) {
    const int sw = (lr & 7) << 3;                     // swizzle, short units
#pragma unroll
    for (int kk = 0; kk < 2; ++kk) {
        const int co = (kk * 32 + quad * 8) ^ sw;
        bf16x8 af[4], bfr[4];
#pragma unroll
        for (int i = 0; i < 4; ++i)
            af[i] = *(const bf16x8*)&sA[(wr + i * 16 + lr) * 64 + co];
#pragma unroll
        for (int j = 0; j < 4; ++j)
            bfr[j] = *(const bf16x8*)&sB[(wc + j * 16 + lr) * 64 + co];
#pragma unroll
        for (int i = 0; i < 4; ++i)
#pragma unroll
            for (int j = 0; j < 4; ++j)
                acc[i * 4 + j] = __builtin_amdgcn_mfma_f32_16x16x32_bf16(af[i], bfr[j], acc[i * 4 + j], 0, 0, 0);
    }
}

__device__ inline void kloop_pipe(const short* __restrict__ A, int lda,
                                  const short* __restrict__ B, int ldb, int Kd,
                                  f32x4* acc, short (*sm)[8192]) {
    const int tid = threadIdx.x, lane = tid & 63, wv = tid >> 6;
    const int quad = lane >> 4, lr = lane & 15;
    const int wr = (wv >> 1) * 64, wc = (wv & 1) * 64;
    const int NT = Kd >> 6;
    stage_tile(A, lda, B, ldb, 0, sm[0], sm[1], tid);
    __builtin_amdgcn_sched_barrier(0);
    asm volatile("s_waitcnt vmcnt(0)" ::: "memory");
    __builtin_amdgcn_sched_barrier(0);
    __builtin_amdgcn_s_barrier();
    __builtin_amdgcn_sched_barrier(0);
    for (int t = 0; t < NT; ++t) {
        const int cur = (t & 1) << 1;                 // 0 or 2
        if (t + 1 < NT)
            stage_tile(A, lda, B, ldb, (t + 1) << 6, sm[cur ^ 2], sm[cur ^ 3], tid);
        __builtin_amdgcn_sched_barrier(0);
        compute_tile(sm[cur], sm[cur + 1], acc, wr, wc, lr, quad);
        __builtin_amdgcn_sched_barrier(0);
        asm volatile("s_waitcnt vmcnt(0)" ::: "memory");
        __builtin_amdgcn_sched_barrier(0);
        __builtin_amdgcn_s_barrier();
        __builtin_amdgcn_sched_barrier(0);
    }
}

__device__ inline void store_out(float* p, float v) { *p = v; }
__device__ inline void store_out(short* p, float v) { *p = f2bf(v); }

template <typename OutT>
__device__ inline void store_tile128(OutT* C, int ldc, const f32x4* acc) {
    const int lane = threadIdx.x & 63, wv = threadIdx.x >> 6;
    const int quad = lane >> 4, lr = lane & 15;
    const int wr = (wv >> 1) * 64, wc = (wv & 1) * 64;
#pragma unroll
    for (int i = 0; i < 4; ++i)
#pragma unroll
        for (int j = 0; j < 4; ++j)
#pragma unroll
            for (int r = 0; r < 4; ++r)
                store_out(&C[(size_t)(wr + i * 16 + quad * 4 + r) * ldc + wc + j * 16 + lr],
                          acc[i * 4 + j][r]);
}

// ---------------- chunked linear attention (C=256, 16 chunks/batch) ----------------

// AM[b,c][v][k] = sum_{t in chunk c} Vt[b][v][t] * Kt[b][k][t]; grid (4,4,64)
__global__ __launch_bounds__(256, 2) void phaseA(const short* __restrict__ Vt,
                                                 const short* __restrict__ Kt,
                                                 short* __restrict__ AM) {
    LDS_DECL;
    const int bc = blockIdx.z, b = bc >> 4, c = bc & 15;
    const short* Ap = Vt + ((size_t)b * 512 + blockIdx.x * 128) * 4096 + c * 256;
    const short* Bp = Kt + ((size_t)b * 512 + blockIdx.y * 128) * 4096 + c * 256;
    short* Cp = AM + (size_t)bc * 262144 + (size_t)blockIdx.x * 128 * 512 + blockIdx.y * 128;
    f32x4 acc[16];
#pragma unroll
    for (int i = 0; i < 16; ++i) acc[i] = (f32x4){0.f, 0.f, 0.f, 0.f};
    kloop_pipe(Ap, 4096, Bp, 4096, 256, acc, sm);
    store_tile128(Cp, 512, acc);
}

// merged: blocks 0..511 = exclusive prefix scan over chunks of AM (memory-bound);
//         blocks 512..767 = P = tril(Q_c K_c^T) (compute-bound) -- independent, overlap.
__global__ __launch_bounds__(256, 2) void scan_phaseS(short* __restrict__ AM,
                                                      const short* __restrict__ Q,
                                                      const short* __restrict__ K,
                                                      short* __restrict__ P) {
    LDS_DECL;
    if (blockIdx.x < 512) {
        int i = blockIdx.x * 256 + threadIdx.x;   // 0..131071
        int b = i >> 15;
        int vk8 = i & 32767;
        size_t base = (size_t)b * 16 * 262144 + (size_t)vk8 * 8;
        float acc[8];
#pragma unroll
        for (int s = 0; s < 8; ++s) acc[s] = 0.f;
        for (int c = 0; c < 16; ++c) {
            short* p = AM + base + (size_t)c * 262144;
            short in8[8];
            *(int4*)in8 = *(const int4*)p;
            short out8[8];
#pragma unroll
            for (int s = 0; s < 8; ++s) out8[s] = f2bf(acc[s]);
            *(int4*)p = *(const int4*)out8;
#pragma unroll
            for (int s = 0; s < 8; ++s) acc[s] += bf2f(in8[s]);
        }
        return;
    }
    const int e = blockIdx.x - 512;               // 0..255
    const int bc = e >> 2, mt = e & 1, nt = (e >> 1) & 1;
    if (mt < nt) return;                          // dead tile (never read)
    const int b = bc >> 4, c = bc & 15;
    short* Pt = P + (size_t)bc * 65536 + (size_t)mt * 128 * 256 + nt * 128;
    const short* Ap = Q + ((size_t)(b * 4096 + c * 256 + mt * 128)) * 512;
    const short* Bp = K + ((size_t)(b * 4096 + c * 256 + nt * 128)) * 512;
    f32x4 acc[16];
#pragma unroll
    for (int i = 0; i < 16; ++i) acc[i] = (f32x4){0.f, 0.f, 0.f, 0.f};
    kloop_pipe(Ap, 512, Bp, 512, 512, acc, sm);
    const int lane = threadIdx.x & 63, wv = threadIdx.x >> 6;
    const int quad = lane >> 4, lr = lane & 15;
    const int wr = (wv >> 1) * 64, wc = (wv & 1) * 64;
    const bool diag = (mt == nt);
#pragma unroll
    for (int i = 0; i < 4; ++i)
#pragma unroll
        for (int j = 0; j < 4; ++j)
#pragma unroll
            for (int r = 0; r < 4; ++r) {
                int t = wr + i * 16 + quad * 4 + r;
                int jj = wc + j * 16 + lr;
                float v = (!diag || jj <= t) ? acc[i * 4 + j][r] : 0.f;
                Pt[(size_t)t * 256 + jj] = f2bf(v);
            }
}

// Y_c = Q_c * Mpre_c^T + tril(P_c) * V_c ; grid (2 mt, 4 nt, 64 bc)
__global__ __launch_bounds__(256, 2) void phaseY(const short* __restrict__ Q,
                                                 const short* __restrict__ Mpre,
                                                 const short* __restrict__ P,
                                                 const short* __restrict__ Vt,
                                                 short* __restrict__ Y) {
    LDS_DECL;
    const int bc = blockIdx.z, b = bc >> 4, c = bc & 15;
    const int mt = blockIdx.x, nt = blockIdx.y;
    f32x4 acc[16];
#pragma unroll
    for (int i = 0; i < 16; ++i) acc[i] = (f32x4){0.f, 0.f, 0.f, 0.f};
    // inter: Y[t][v] += sum_k Q[t][k] * Mpre[v][k]
    const short* Ai = Q + ((size_t)(b * 4096 + c * 256 + mt * 128)) * 512;
    const short* Bi = Mpre + (size_t)bc * 262144 + (size_t)nt * 128 * 512;
    kloop_pipe(Ai, 512, Bi, 512, 512, acc, sm);
    // intra: Y[t][v] += sum_j P[t][j] * Vt[v][j]; for mt=0 only j<128 nonzero
    const short* Ap = P + (size_t)bc * 65536 + (size_t)mt * 128 * 256;
    const short* Bv = Vt + ((size_t)b * 512 + nt * 128) * 4096 + c * 256;
    kloop_pipe(Ap, 256, Bv, 4096, (mt + 1) * 128, acc, sm);
    short* Cp = Y + ((size_t)(b * 4096 + c * 256 + mt * 128)) * 512 + nt * 128;
    store_tile128(Cp, 512, acc);
}

// generic C[M,N] = A . Bt^T (output projection)
template <typename OutT>
__global__ __launch_bounds__(256, 2) void gemm128(const short* __restrict__ A, int lda,
                                                  const short* __restrict__ B, int ldb,
                                                  OutT* __restrict__ C, int ldc, int Kd) {
    LDS_DECL;
    const short* At = A + (size_t)blockIdx.x * 128 * lda;
    const short* Bt = B + (size_t)blockIdx.y * 128 * ldb;
    OutT* Ct = C + (size_t)blockIdx.x * 128 * ldc + blockIdx.y * 128;
    f32x4 acc[16];
#pragma unroll
    for (int i = 0; i < 16; ++i) acc[i] = (f32x4){0.f, 0.f, 0.f, 0.f};
    kloop_pipe(At, lda, Bt, ldb, Kd, acc, sm);
    store_tile128(Ct, ldc, acc);
}

// ---------------- host ----------------

extern "C" void kernel_launch(void* const* d_in, const int* in_sizes, int n_in,
                              void* d_out, int out_size, void* d_ws, size_t ws_size,
                              hipStream_t stream) {
    const float* x  = (const float*)d_in[0];
    const float* Wq = (const float*)d_in[1];
    const float* Wk = (const float*)d_in[2];
    const float* Wv = (const float*)d_in[3];
    const float* Wo = (const float*)d_in[4];
    float* out = (float*)d_out;

    const size_t NTD = 16384 * 512;   // 8,388,608 elems

    short* ws  = (short*)d_ws;
    short* Xb  = ws;                  // 8.39M
    short* Qb  = Xb + NTD;
    short* Kb  = Qb + NTD;
    short* Kt  = Kb + NTD;
    short* Vt  = Kt + NTD;
    short* P   = Vt + NTD;            // 4.19M
    short* W4T = P + 4194304;         // 1.05M : WqT|WkT|WvT|WoT
    short* AM  = W4T + 1048576;       // 16.78M
    short* Yb  = Kb;                  // Kb dead after scan_phaseS

    short* WoT = W4T + 3 * 262144;

    prep_kernel<<<12288, 256, 0, stream>>>(x, Xb, Wq, Wk, Wv, Wo, W4T);
    proj_qkv<<<384, 512, 0, stream>>>(Xb, W4T, Qb, Kb, Vt, Kt);
    phaseA<<<dim3(4, 4, 64), 256, 0, stream>>>(Vt, Kt, AM);
    scan_phaseS<<<768, 256, 0, stream>>>(AM, Qb, Kb, P);
    phaseY<<<dim3(2, 4, 64), 256, 0, stream>>>(Qb, AM, P, Vt, Yb);
    gemm128<float><<<dim3(128, 4), 256, 0, stream>>>(Yb, 512, WoT, 512, out, 512, 512);
}

// Round 4
// 230.103 us; speedup vs baseline: 1.0059x; 1.0059x over previous
//
#include <hip/hip_runtime.h>
#include <hip/hip_bf16.h>

typedef __attribute__((ext_vector_type(8))) short bf16x8;
typedef __attribute__((ext_vector_type(4))) float f32x4;

__device__ inline short f2bf(float f) {
    __hip_bfloat16 h = __float2bfloat16(f);
    short s;
    __builtin_memcpy(&s, &h, 2);
    return s;
}
__device__ inline float bf2f(short s) {
    unsigned int u = ((unsigned int)(unsigned short)s) << 16;
    float f;
    __builtin_memcpy(&f, &u, 4);
    return f;
}

// async 16B global->LDS; dest must be wave-uniform base + lane*16
__device__ inline void cp16_async(const void* g, void* l) {
    __builtin_amdgcn_global_load_lds(
        (const __attribute__((address_space(1))) void*)g,
        (__attribute__((address_space(3))) void*)l, 16, 0, 0);
}

// ---------------- prep: cast x + transpose-cast all 4 weights ----------------

__global__ void prep_kernel(const float* __restrict__ x, short* __restrict__ Xb,
                            const float* __restrict__ W0, const float* __restrict__ W1,
                            const float* __restrict__ W2, const float* __restrict__ W3,
                            short* __restrict__ W4T) {
    int bid = blockIdx.x;
    if (bid < 8192) {
        int i = bid * 256 + threadIdx.x;
        float4 f = ((const float4*)x)[i];
        union { short s[4]; int2 v; } u;
        u.s[0] = f2bf(f.x); u.s[1] = f2bf(f.y); u.s[2] = f2bf(f.z); u.s[3] = f2bf(f.w);
        ((int2*)Xb)[i] = u.v;
    } else {
        int i = (bid - 8192) * 256 + threadIdx.x;
        int w = i >> 18;
        int r = i & 262143;
        int n = r >> 9, k = r & 511;
        const float* W = (w == 0) ? W0 : (w == 1) ? W1 : (w == 2) ? W2 : W3;
        W4T[i] = f2bf(W[k * 512 + n]);
    }
}

// ========== 128x128 core, BK=32, 4-deep counted-vmcnt pipeline ==========
// LDS: 4 buffers x (A 8KB + B 8KB) = 64KB -> 2 blocks/CU at 256 threads.
// Iter t: stage(t+3) -> compute(t) -> s_waitcnt vmcnt(8) -> s_barrier.
//   Per-tile loads/thread = 4 (2 A + 2 B). In-order retirement invariant:
//   entering iter t, outstanding = {t+1:4, t+2:4}, tile t LANDED (waited
//   two iters ago). vmcnt(8) after compute retires exactly tile t+1's 4.
//   Tail: t+3>=NT -> no stage; wait 4 if only t+2 in flight, else 0.
// Buffer hazard: stage(t+3) writes buf[(t+3)&3] = buf[(t-1)&3], whose
//   readers (compute(t-1)) all passed barrier(t-1) before this stage. Safe
//   with ONE barrier per iteration (same protection as proven round-2 loop).
// Rows are 64B (32 bf16); XOR swizzle byte ^= (row&3)<<4 via pre-swizzled
// GLOBAL source col (dest stays linear), undone on ds_read. Residual 4-way.

#define LDS_DECL __shared__ short sm[8][4096]
// sm[2b] = A buf b (128x32), sm[2b+1] = B buf b, b = 0..3

__device__ inline void stage32(const short* __restrict__ A, int lda,
                               const short* __restrict__ B, int ldb, int k0,
                               short* sA, short* sB, int tid) {
#pragma unroll
    for (int j = 0; j < 2; ++j) {
        const int L = tid * 16 + j * 4096;            // linear byte in 8KB tile
        const int row = L >> 6;                       // 64B per row (32 bf16)
        const int cb = (L & 63) ^ ((row & 3) << 4);   // inverse-swizzled src col (bytes)
        cp16_async((const char*)(A + (size_t)row * lda + k0) + cb, (char*)sA + L);
        cp16_async((const char*)(B + (size_t)row * ldb + k0) + cb, (char*)sB + L);
    }
}

__device__ inline void compute32(const short* sA, const short* sB, f32x4* acc,
                                 int wr, int wc, int lr, int quad) {
    const int cb = (quad * 16) ^ ((lr & 3) << 4);     // byte col (row&3 == lr&3)
    bf16x8 af[4], bfr[4];
#pragma unroll
    for (int i = 0; i < 4; ++i)
        af[i] = *(const bf16x8*)((const char*)sA + (wr + i * 16 + lr) * 64 + cb);
#pragma unroll
    for (int j = 0; j < 4; ++j)
        bfr[j] = *(const bf16x8*)((const char*)sB + (wc + j * 16 + lr) * 64 + cb);
#pragma unroll
    for (int i = 0; i < 4; ++i)
#pragma unroll
        for (int j = 0; j < 4; ++j)
            acc[i * 4 + j] = __builtin_amdgcn_mfma_f32_16x16x32_bf16(af[i], bfr[j], acc[i * 4 + j], 0, 0, 0);
}

__device__ inline void kloop_pipe(const short* __restrict__ A, int lda,
                                  const short* __restrict__ B, int ldb, int Kd,
                                  f32x4* acc, short (*sm)[4096]) {
    const int tid = threadIdx.x, lane = tid & 63, wv = tid >> 6;
    const int quad = lane >> 4, lr = lane & 15;
    const int wr = (wv >> 1) * 64, wc = (wv & 1) * 64;
    const int NT = Kd >> 5;                           // BK = 32; NT >= 4 for all callers
    // prologue: stage tiles 0,1,2 then ensure tile 0 landed (12 out -> wait 8)
    stage32(A, lda, B, ldb, 0,  sm[0], sm[1], tid);
    stage32(A, lda, B, ldb, 32, sm[2], sm[3], tid);
    stage32(A, lda, B, ldb, 64, sm[4], sm[5], tid);
    __builtin_amdgcn_sched_barrier(0);
    asm volatile("s_waitcnt vmcnt(8)" ::: "memory");
    __builtin_amdgcn_sched_barrier(0);
    __builtin_amdgcn_s_barrier();
    __builtin_amdgcn_sched_barrier(0);
    for (int t = 0; t < NT; ++t) {
        const int cur = (t & 3) << 1;
        if (t + 3 < NT)                               // stage tile t+3 into buf[(t+3)&3]
            stage32(A, lda, B, ldb, (t + 3) << 5,
                    sm[((t + 3) & 3) << 1], sm[(((t + 3) & 3) << 1) + 1], tid);
        __builtin_amdgcn_sched_barrier(0);
        compute32(sm[cur], sm[cur + 1], acc, wr, wc, lr, quad);
        __builtin_amdgcn_sched_barrier(0);
        if (t + 3 < NT) {                             // {t+1,t+2,t+3} in flight: retire t+1
            asm volatile("s_waitcnt vmcnt(8)" ::: "memory");
        } else if (t + 2 < NT) {                      // {t+1,t+2}: retire t+1
            asm volatile("s_waitcnt vmcnt(4)" ::: "memory");
        } else {                                      // only t+1 (or none): drain
            asm volatile("s_waitcnt vmcnt(0)" ::: "memory");
        }
        __builtin_amdgcn_sched_barrier(0);
        __builtin_amdgcn_s_barrier();                 // buf[(t+1)&3] ready; readers of t done
        __builtin_amdgcn_sched_barrier(0);
    }
    // returns fully drained (tail waits vmcnt(0)) + barriered -> safe to re-enter
}

__device__ inline void store_out(float* p, float v) { *p = v; }
__device__ inline void store_out(short* p, float v) { *p = f2bf(v); }

template <typename OutT>
__device__ inline void store_tile128(OutT* C, int ldc, const f32x4* acc) {
    const int lane = threadIdx.x & 63, wv = threadIdx.x >> 6;
    const int quad = lane >> 4, lr = lane & 15;
    const int wr = (wv >> 1) * 64, wc = (wv & 1) * 64;
#pragma unroll
    for (int i = 0; i < 4; ++i)
#pragma unroll
        for (int j = 0; j < 4; ++j)
#pragma unroll
            for (int r = 0; r < 4; ++r)
                store_out(&C[(size_t)(wr + i * 16 + quad * 4 + r) * ldc + wc + j * 16 + lr],
                          acc[i * 4 + j][r]);
}

// ---------------- unified projections ----------------
// grid 1536 blocks:
//   0..1023   : row-major Q|K: mt = bid>>3 (0..127), by = bid&7 (<4 -> Q cols, else K cols)
//               K blocks additionally scatter Kt[b][f][t] from registers.
//   1024..1535: Vt (feature-major): r = bid-1024 -> b = r&3, tt = (r>>2)&31, ft = r>>7
__global__ __launch_bounds__(256, 2) void proj_all(const short* __restrict__ Xb,
                                                   const short* __restrict__ W4T,
                                                   short* __restrict__ Qb, short* __restrict__ Kb,
                                                   short* __restrict__ Vt, short* __restrict__ Kt) {
    LDS_DECL;
    f32x4 acc[16];
#pragma unroll
    for (int i = 0; i < 16; ++i) acc[i] = (f32x4){0.f, 0.f, 0.f, 0.f};
    const int bid = blockIdx.x;
    const int lane = threadIdx.x & 63, wv = threadIdx.x >> 6;
    const int quad = lane >> 4, lr = lane & 15;
    const int wr = (wv >> 1) * 64, wc = (wv & 1) * 64;
    if (bid < 1024) {
        const int mt = bid >> 3, by = bid & 7;
        const short* At = Xb + (size_t)mt * 128 * 512;
        const short* Bt = W4T + (size_t)by * 128 * 512;   // by<4: Wq cols, else Wk cols
        short* Ct = ((by < 4) ? Qb : Kb) + (size_t)mt * 128 * 512 + (by & 3) * 128;
        kloop_pipe(At, 512, Bt, 512, 512, acc, sm);
        store_tile128(Ct, 512, acc);
        if (by >= 4) {
            // emit Kt[b][f][t] from registers (int2 scatter; block covers full
            // 128-t span per f, so L2 assembles complete lines -> no HBM overfetch)
            const int b = mt >> 5;
            const int t0b = (mt & 31) * 128;
            const int f0 = (by - 4) * 128;
#pragma unroll
            for (int i = 0; i < 4; ++i)
#pragma unroll
                for (int j = 0; j < 4; ++j) {
                    int f = f0 + wc + j * 16 + lr;
                    int tt0 = t0b + wr + i * 16 + quad * 4;
                    short tmp[4];
#pragma unroll
                    for (int r = 0; r < 4; ++r) tmp[r] = f2bf(acc[i * 4 + j][r]);
                    *(int2*)&Kt[((size_t)b * 512 + f) * 4096 + tt0] = *(const int2*)tmp;
                }
        }
    } else {
        const int r = bid - 1024;
        const int b = r & 3, tt = (r >> 2) & 31, ft = r >> 7;
        const short* At = W4T + (size_t)2 * 262144 + (size_t)ft * 128 * 512;   // Wv
        const short* Bt = Xb + ((size_t)b * 4096 + tt * 128) * 512;
        short* Ct = Vt + (size_t)b * 512 * 4096 + (size_t)ft * 128 * 4096 + tt * 128;
        kloop_pipe(At, 512, Bt, 512, 512, acc, sm);
        store_tile128(Ct, 4096, acc);
    }
}

// ---------------- chunked linear attention (C=256, 16 chunks/batch) ----------------

// AM[b,c][v][k] = sum_{t in chunk c} Vt[b][v][t] * Kt[b][k][t]; grid (4,4,64)
__global__ __launch_bounds__(256, 2) void phaseA(const short* __restrict__ Vt,
                                                 const short* __restrict__ Kt,
                                                 short* __restrict__ AM) {
    LDS_DECL;
    const int bc = blockIdx.z, b = bc >> 4, c = bc & 15;
    const short* Ap = Vt + ((size_t)b * 512 + blockIdx.x * 128) * 4096 + c * 256;
    const short* Bp = Kt + ((size_t)b * 512 + blockIdx.y * 128) * 4096 + c * 256;
    short* Cp = AM + (size_t)bc * 262144 + (size_t)blockIdx.x * 128 * 512 + blockIdx.y * 128;
    f32x4 acc[16];
#pragma unroll
    for (int i = 0; i < 16; ++i) acc[i] = (f32x4){0.f, 0.f, 0.f, 0.f};
    kloop_pipe(Ap, 4096, Bp, 4096, 256, acc, sm);
    store_tile128(Cp, 512, acc);
}

// merged: blocks 0..511 = exclusive prefix scan over chunks of AM (memory-bound);
//         blocks 512..767 = P = tril(Q_c K_c^T) (compute-bound) -- independent, overlap.
__global__ __launch_bounds__(256, 2) void scan_phaseS(short* __restrict__ AM,
                                                      const short* __restrict__ Q,
                                                      const short* __restrict__ K,
                                                      short* __restrict__ P) {
    LDS_DECL;
    if (blockIdx.x < 512) {
        int i = blockIdx.x * 256 + threadIdx.x;   // 0..131071
        int b = i >> 15;
        int vk8 = i & 32767;
        size_t base = (size_t)b * 16 * 262144 + (size_t)vk8 * 8;
        float acc[8];
#pragma unroll
        for (int s = 0; s < 8; ++s) acc[s] = 0.f;
        for (int c = 0; c < 16; ++c) {
            short* p = AM + base + (size_t)c * 262144;
            short in8[8];
            *(int4*)in8 = *(const int4*)p;
            short out8[8];
#pragma unroll
            for (int s = 0; s < 8; ++s) out8[s] = f2bf(acc[s]);
            *(int4*)p = *(const int4*)out8;
#pragma unroll
            for (int s = 0; s < 8; ++s) acc[s] += bf2f(in8[s]);
        }
        return;
    }
    const int e = blockIdx.x - 512;               // 0..255
    const int bc = e >> 2, mt = e & 1, nt = (e >> 1) & 1;
    if (mt < nt) return;                          // dead tile (never read)
    const int b = bc >> 4, c = bc & 15;
    short* Pt = P + (size_t)bc * 65536 + (size_t)mt * 128 * 256 + nt * 128;
    const short* Ap = Q + ((size_t)(b * 4096 + c * 256 + mt * 128)) * 512;
    const short* Bp = K + ((size_t)(b * 4096 + c * 256 + nt * 128)) * 512;
    f32x4 acc[16];
#pragma unroll
    for (int i = 0; i < 16; ++i) acc[i] = (f32x4){0.f, 0.f, 0.f, 0.f};
    kloop_pipe(Ap, 512, Bp, 512, 512, acc, sm);
    const int lane = threadIdx.x & 63, wv = threadIdx.x >> 6;
    const int quad = lane >> 4, lr = lane & 15;
    const int wr = (wv >> 1) * 64, wc = (wv & 1) * 64;
    const bool diag = (mt == nt);
#pragma unroll
    for (int i = 0; i < 4; ++i)
#pragma unroll
        for (int j = 0; j < 4; ++j)
#pragma unroll
            for (int r = 0; r < 4; ++r) {
                int t = wr + i * 16 + quad * 4 + r;
                int jj = wc + j * 16 + lr;
                float v = (!diag || jj <= t) ? acc[i * 4 + j][r] : 0.f;
                Pt[(size_t)t * 256 + jj] = f2bf(v);
            }
}

// Y_c = Q_c * Mpre_c^T + tril(P_c) * V_c ; grid (2 mt, 4 nt, 64 bc)
__global__ __launch_bounds__(256, 2) void phaseY(const short* __restrict__ Q,
                                                 const short* __restrict__ Mpre,
                                                 const short* __restrict__ P,
                                                 const short* __restrict__ Vt,
                                                 short* __restrict__ Y) {
    LDS_DECL;
    const int bc = blockIdx.z, b = bc >> 4, c = bc & 15;
    const int mt = blockIdx.x, nt = blockIdx.y;
    f32x4 acc[16];
#pragma unroll
    for (int i = 0; i < 16; ++i) acc[i] = (f32x4){0.f, 0.f, 0.f, 0.f};
    // inter: Y[t][v] += sum_k Q[t][k] * Mpre[v][k]
    const short* Ai = Q + ((size_t)(b * 4096 + c * 256 + mt * 128)) * 512;
    const short* Bi = Mpre + (size_t)bc * 262144 + (size_t)nt * 128 * 512;
    kloop_pipe(Ai, 512, Bi, 512, 512, acc, sm);
    // intra: Y[t][v] += sum_j P[t][j] * Vt[v][j]; for mt=0 only j<128 nonzero
    // (first call exits drained + barriered -> safe to re-enter)
    const short* Ap = P + (size_t)bc * 65536 + (size_t)mt * 128 * 256;
    const short* Bv = Vt + ((size_t)b * 512 + nt * 128) * 4096 + c * 256;
    kloop_pipe(Ap, 256, Bv, 4096, (mt + 1) * 128, acc, sm);
    short* Cp = Y + ((size_t)(b * 4096 + c * 256 + mt * 128)) * 512 + nt * 128;
    store_tile128(Cp, 512, acc);
}

// generic C[M,N] = A . Bt^T (output projection)
template <typename OutT>
__global__ __launch_bounds__(256, 2) void gemm128(const short* __restrict__ A, int lda,
                                                  const short* __restrict__ B, int ldb,
                                                  OutT* __restrict__ C, int ldc, int Kd) {
    LDS_DECL;
    const short* At = A + (size_t)blockIdx.x * 128 * lda;
    const short* Bt = B + (size_t)blockIdx.y * 128 * ldb;
    OutT* Ct = C + (size_t)blockIdx.x * 128 * ldc + blockIdx.y * 128;
    f32x4 acc[16];
#pragma unroll
    for (int i = 0; i < 16; ++i) acc[i] = (f32x4){0.f, 0.f, 0.f, 0.f};
    kloop_pipe(At, lda, Bt, ldb, Kd, acc, sm);
    store_tile128(Ct, ldc, acc);
}

// ---------------- host ----------------

extern "C" void kernel_launch(void* const* d_in, const int* in_sizes, int n_in,
                              void* d_out, int out_size, void* d_ws, size_t ws_size,
                              hipStream_t stream) {
    const float* x  = (const float*)d_in[0];
    const float* Wq = (const float*)d_in[1];
    const float* Wk = (const float*)d_in[2];
    const float* Wv = (const float*)d_in[3];
    const float* Wo = (const float*)d_in[4];
    float* out = (float*)d_out;

    const size_t NTD = 16384 * 512;   // 8,388,608 elems

    short* ws  = (short*)d_ws;
    short* Xb  = ws;                  // 8.39M
    short* Qb  = Xb + NTD;
    short* Kb  = Qb + NTD;
    short* Kt  = Kb + NTD;
    short* Vt  = Kt + NTD;
    short* P   = Vt + NTD;            // 4.19M
    short* W4T = P + 4194304;         // 1.05M : WqT|WkT|WvT|WoT
    short* AM  = W4T + 1048576;       // 16.78M
    short* Yb  = Kb;                  // Kb dead after scan_phaseS

    short* WoT = W4T + 3 * 262144;

    prep_kernel<<<12288, 256, 0, stream>>>(x, Xb, Wq, Wk, Wv, Wo, W4T);
    proj_all<<<1536, 256, 0, stream>>>(Xb, W4T, Qb, Kb, Vt, Kt);
    phaseA<<<dim3(4, 4, 64), 256, 0, stream>>>(Vt, Kt, AM);
    scan_phaseS<<<768, 256, 0, stream>>>(AM, Qb, Kb, P);
    phaseY<<<dim3(2, 4, 64), 256, 0, stream>>>(Qb, AM, P, Vt, Yb);
    gemm128<float><<<dim3(128, 4), 256, 0, stream>>>(Yb, 512, WoT, 512, out, 512, 512);
}

// Round 5
// 223.724 us; speedup vs baseline: 1.0346x; 1.0285x over previous
//
#include <hip/hip_runtime.h>
#include <hip/hip_bf16.h>

typedef __attribute__((ext_vector_type(8))) short bf16x8;
typedef __attribute__((ext_vector_type(4))) float f32x4;

__device__ inline short f2bf(float f) {
    __hip_bfloat16 h = __float2bfloat16(f);
    short s;
    __builtin_memcpy(&s, &h, 2);
    return s;
}
__device__ inline float bf2f(short s) {
    unsigned int u = ((unsigned int)(unsigned short)s) << 16;
    float f;
    __builtin_memcpy(&f, &u, 4);
    return f;
}

// async 16B global->LDS; dest must be wave-uniform base + lane*16
__device__ inline void cp16_async(const void* g, void* l) {
    __builtin_amdgcn_global_load_lds(
        (const __attribute__((address_space(1))) void*)g,
        (__attribute__((address_space(3))) void*)l, 16, 0, 0);
}

// ---------------- prep ----------------
// bid < 4096        : Xp packed fragments [mt 0..127][kb 0..63][row 0..127] of 16B
//                     (element e of frag = bf16(x[mt*128+row][kb*8+e]))
// 4096 <= bid < 4480: PW packed QKV weight frags [nn 0..95][ks 0..15][lane 0..63]
//                     frag e = bf16(W_w[k=ks*32+(lane>>4)*8+e][n=(nn&31)*16+(lane&15)])
//                     w = nn>>5 (Wq,Wk,Wv)
// else              : WoT row-major transpose-cast (unchanged consumer: gemm128)
__global__ void prep_kernel(const float* __restrict__ x, short* __restrict__ Xp,
                            const float* __restrict__ W0, const float* __restrict__ W1,
                            const float* __restrict__ W2, const float* __restrict__ W3,
                            short* __restrict__ PW, short* __restrict__ WoT) {
    int bid = blockIdx.x;
    if (bid < 4096) {
        int f = bid * 256 + threadIdx.x;           // 0..1,048,575
        int mtf = f >> 13, r = f & 8191, kb = r >> 7, row = r & 127;
        const float* src = x + ((size_t)(mtf * 128 + row) * 512 + kb * 8);
        float4 a = ((const float4*)src)[0];
        float4 bq = ((const float4*)src)[1];
        short t[8];
        t[0] = f2bf(a.x);  t[1] = f2bf(a.y);  t[2] = f2bf(a.z);  t[3] = f2bf(a.w);
        t[4] = f2bf(bq.x); t[5] = f2bf(bq.y); t[6] = f2bf(bq.z); t[7] = f2bf(bq.w);
        ((int4*)Xp)[f] = *(const int4*)t;
    } else if (bid < 4480) {
        int g = (bid - 4096) * 256 + threadIdx.x;  // 0..98303
        int lane = g & 63, ksg = (g >> 6) & 15, nn = g >> 10;
        int w = nn >> 5;
        int nl = (nn & 31) * 16 + (lane & 15);
        int k0 = ksg * 32 + (lane >> 4) * 8;
        const float* W = (w == 0) ? W0 : (w == 1) ? W1 : W2;
        short t[8];
#pragma unroll
        for (int e = 0; e < 8; ++e) t[e] = f2bf(W[(size_t)(k0 + e) * 512 + nl]);
        ((int4*)PW)[g] = *(const int4*)t;
    } else {
        int i = (bid - 4480) * 256 + threadIdx.x;  // 0..262143
        int n = i >> 9, k = i & 511;
        WoT[i] = f2bf(W3[k * 512 + n]);
    }
}

// ========== NEW proj core: persistent X-panel in LDS + packed-B register stream ==========
// Block: 512 thr (8 waves, 2 wm x 4 wn), output 128 rows x 768 cols, grid 256 = 128mt x 2half.
// X panel (128x512 bf16 = 128 KB) staged ONCE (contiguous memcpy of packed frags);
// weights streamed to registers from PW (perfectly coalesced, L2-resident 1.5 MB).
// Main loop has NO barriers / NO waitcnt: LDS read-only after a 2-phase staged prologue.
// A-frag ds_reads are linear in lane (K-major frag layout) -> zero bank conflicts.

#define KSTEP(ks) { \
    bf16x8 af[4], bfr[4]; \
    _Pragma("unroll") for (int i = 0; i < 4; ++i) \
        af[i] = *(const bf16x8*)&Xs[((ks) * 512 + quad * 128 + wm * 64 + i * 16 + lr) * 8]; \
    _Pragma("unroll") for (int j = 0; j < 4; ++j) \
        bfr[j] = *(const bf16x8*)&PB[((size_t)((j * 16 + (ks)) * 64 + lane)) * 8]; \
    _Pragma("unroll") for (int i = 0; i < 4; ++i) \
        _Pragma("unroll") for (int j = 0; j < 4; ++j) \
            acc[i * 4 + j] = __builtin_amdgcn_mfma_f32_16x16x32_bf16(af[i], bfr[j], acc[i * 4 + j], 0, 0, 0); }

__global__ __launch_bounds__(512, 2) void proj_qkv(const short* __restrict__ Xp,
                                                   const short* __restrict__ PW,
                                                   short* __restrict__ Qb, short* __restrict__ Kb,
                                                   short* __restrict__ Vt, short* __restrict__ Kt) {
    __shared__ short Xs[65536];                    // 128 KB, frag idx = kb*128 + row
    const int tid = threadIdx.x, lane = tid & 63, wv = tid >> 6;
    const int lr = lane & 15, quad = lane >> 4;
    const int wm = wv >> 2, wn = wv & 3;
    const int bid = blockIdx.x;
    const int swz = (bid & 7) * 32 + (bid >> 3);   // bijective XCD swizzle (256 = 8*32);
    const int mt = swz >> 1, half = swz & 1;       // both halves of an mt share an XCD
    // ---- stage whole panel: frag f = j*512+tid ; first 8 j-groups = kb 0..31 (K first half)
    const short* Ap = Xp + (size_t)mt * 65536;     // 8192 frags * 8 shorts
#pragma unroll
    for (int j = 0; j < 8; ++j) {
        const int f = j * 512 + tid;
        cp16_async(Ap + (size_t)f * 8, (char*)Xs + f * 16);
    }
    __builtin_amdgcn_sched_barrier(0);             // keep halves ordered for counted wait
#pragma unroll
    for (int j = 8; j < 16; ++j) {
        const int f = j * 512 + tid;
        cp16_async(Ap + (size_t)f * 8, (char*)Xs + f * 16);
    }
    __builtin_amdgcn_sched_barrier(0);
    const int b = mt >> 5;
    const int tl0 = (mt & 31) * 128 + wm * 64;
    const int trow0 = mt * 128 + wm * 64;
    for (int pass = 0; pass < 3; ++pass) {
        const int gc0 = half * 768 + pass * 256;   // global col base of this 256-col pass
        f32x4 acc[16];
#pragma unroll
        for (int i = 0; i < 16; ++i) acc[i] = (f32x4){0.f, 0.f, 0.f, 0.f};
        const short* PB = PW + (size_t)((gc0 >> 4) + wn * 4) * 8192;  // nn0 * 16*64*8
        if (pass == 0) {
            asm volatile("s_waitcnt vmcnt(8)" ::: "memory");   // kb 0..31 landed (own wave)
            __builtin_amdgcn_sched_barrier(0);
            __builtin_amdgcn_s_barrier();                      // ... for ALL waves
            __builtin_amdgcn_sched_barrier(0);
#pragma unroll 4
            for (int ks = 0; ks < 8; ++ks) KSTEP(ks)
            __builtin_amdgcn_sched_barrier(0);
            asm volatile("s_waitcnt vmcnt(0)" ::: "memory");   // rest of panel landed
            __builtin_amdgcn_sched_barrier(0);
            __builtin_amdgcn_s_barrier();
            __builtin_amdgcn_sched_barrier(0);
#pragma unroll 4
            for (int ks = 8; ks < 16; ++ks) KSTEP(ks)
        } else {                                   // X fully resident: barrier-free
#pragma unroll 4
            for (int ks = 0; ks < 16; ++ks) KSTEP(ks)
        }
        // ---- epilogue for this 256-col pass (stores overlap next pass's compute)
        const int p = gc0 >> 9;                    // 0=Q 1=K 2=V (pass never crosses)
        const int fc0 = (gc0 & 511) + wn * 64;
        if (p < 2) {                               // Q or K row-major [t][f]
            short* C = p ? Kb : Qb;
#pragma unroll
            for (int i = 0; i < 4; ++i)
#pragma unroll
                for (int j = 0; j < 4; ++j) {
                    const size_t base = (size_t)(trow0 + i * 16 + quad * 4) * 512 + fc0 + j * 16 + lr;
#pragma unroll
                    for (int r = 0; r < 4; ++r)
                        C[base + (size_t)r * 512] = f2bf(acc[i * 4 + j][r]);
                }
        }
        if (p >= 1) {                              // Kt / Vt feature-major [b][f][t]
            short* T = (p == 1) ? Kt : Vt;
#pragma unroll
            for (int i = 0; i < 4; ++i)
#pragma unroll
                for (int j = 0; j < 4; ++j) {
                    const int f = fc0 + j * 16 + lr;
                    short tmp[4];
#pragma unroll
                    for (int r = 0; r < 4; ++r) tmp[r] = f2bf(acc[i * 4 + j][r]);
                    *(int2*)&T[((size_t)b * 512 + f) * 4096 + tl0 + i * 16 + quad * 4] = *(const int2*)tmp;
                }
        }
    }
}

// ========== 128x128 core, BK=32, 4-deep counted-vmcnt pipeline (round-4, passing) ==========

#define LDS_DECL __shared__ short sm[8][4096]
// sm[2b] = A buf b (128x32), sm[2b+1] = B buf b, b = 0..3

__device__ inline void stage32(const short* __restrict__ A, int lda,
                               const short* __restrict__ B, int ldb, int k0,
                               short* sA, short* sB, int tid) {
#pragma unroll
    for (int j = 0; j < 2; ++j) {
        const int L = tid * 16 + j * 4096;            // linear byte in 8KB tile
        const int row = L >> 6;                       // 64B per row (32 bf16)
        const int cb = (L & 63) ^ ((row & 3) << 4);   // inverse-swizzled src col (bytes)
        cp16_async((const char*)(A + (size_t)row * lda + k0) + cb, (char*)sA + L);
        cp16_async((const char*)(B + (size_t)row * ldb + k0) + cb, (char*)sB + L);
    }
}

__device__ inline void compute32(const short* sA, const short* sB, f32x4* acc,
                                 int wr, int wc, int lr, int quad) {
    const int cb = (quad * 16) ^ ((lr & 3) << 4);     // byte col (row&3 == lr&3)
    bf16x8 af[4], bfr[4];
#pragma unroll
    for (int i = 0; i < 4; ++i)
        af[i] = *(const bf16x8*)((const char*)sA + (wr + i * 16 + lr) * 64 + cb);
#pragma unroll
    for (int j = 0; j < 4; ++j)
        bfr[j] = *(const bf16x8*)((const char*)sB + (wc + j * 16 + lr) * 64 + cb);
#pragma unroll
    for (int i = 0; i < 4; ++i)
#pragma unroll
        for (int j = 0; j < 4; ++j)
            acc[i * 4 + j] = __builtin_amdgcn_mfma_f32_16x16x32_bf16(af[i], bfr[j], acc[i * 4 + j], 0, 0, 0);
}

__device__ inline void kloop_pipe(const short* __restrict__ A, int lda,
                                  const short* __restrict__ B, int ldb, int Kd,
                                  f32x4* acc, short (*sm)[4096]) {
    const int tid = threadIdx.x, lane = tid & 63, wv = tid >> 6;
    const int quad = lane >> 4, lr = lane & 15;
    const int wr = (wv >> 1) * 64, wc = (wv & 1) * 64;
    const int NT = Kd >> 5;                           // BK = 32; NT >= 4 for all callers
    stage32(A, lda, B, ldb, 0,  sm[0], sm[1], tid);
    stage32(A, lda, B, ldb, 32, sm[2], sm[3], tid);
    stage32(A, lda, B, ldb, 64, sm[4], sm[5], tid);
    __builtin_amdgcn_sched_barrier(0);
    asm volatile("s_waitcnt vmcnt(8)" ::: "memory");
    __builtin_amdgcn_sched_barrier(0);
    __builtin_amdgcn_s_barrier();
    __builtin_amdgcn_sched_barrier(0);
    for (int t = 0; t < NT; ++t) {
        const int cur = (t & 3) << 1;
        if (t + 3 < NT)
            stage32(A, lda, B, ldb, (t + 3) << 5,
                    sm[((t + 3) & 3) << 1], sm[(((t + 3) & 3) << 1) + 1], tid);
        __builtin_amdgcn_sched_barrier(0);
        compute32(sm[cur], sm[cur + 1], acc, wr, wc, lr, quad);
        __builtin_amdgcn_sched_barrier(0);
        if (t + 3 < NT) {
            asm volatile("s_waitcnt vmcnt(8)" ::: "memory");
        } else if (t + 2 < NT) {
            asm volatile("s_waitcnt vmcnt(4)" ::: "memory");
        } else {
            asm volatile("s_waitcnt vmcnt(0)" ::: "memory");
        }
        __builtin_amdgcn_sched_barrier(0);
        __builtin_amdgcn_s_barrier();
        __builtin_amdgcn_sched_barrier(0);
    }
}

__device__ inline void store_out(float* p, float v) { *p = v; }
__device__ inline void store_out(short* p, float v) { *p = f2bf(v); }

template <typename OutT>
__device__ inline void store_tile128(OutT* C, int ldc, const f32x4* acc) {
    const int lane = threadIdx.x & 63, wv = threadIdx.x >> 6;
    const int quad = lane >> 4, lr = lane & 15;
    const int wr = (wv >> 1) * 64, wc = (wv & 1) * 64;
#pragma unroll
    for (int i = 0; i < 4; ++i)
#pragma unroll
        for (int j = 0; j < 4; ++j)
#pragma unroll
            for (int r = 0; r < 4; ++r)
                store_out(&C[(size_t)(wr + i * 16 + quad * 4 + r) * ldc + wc + j * 16 + lr],
                          acc[i * 4 + j][r]);
}

// ---------------- chunked linear attention (C=256, 16 chunks/batch) ----------------

// AM[b,c][v][k] = sum_{t in chunk c} Vt[b][v][t] * Kt[b][k][t]; grid (4,4,64)
__global__ __launch_bounds__(256, 2) void phaseA(const short* __restrict__ Vt,
                                                 const short* __restrict__ Kt,
                                                 short* __restrict__ AM) {
    LDS_DECL;
    const int bc = blockIdx.z, b = bc >> 4, c = bc & 15;
    const short* Ap = Vt + ((size_t)b * 512 + blockIdx.x * 128) * 4096 + c * 256;
    const short* Bp = Kt + ((size_t)b * 512 + blockIdx.y * 128) * 4096 + c * 256;
    short* Cp = AM + (size_t)bc * 262144 + (size_t)blockIdx.x * 128 * 512 + blockIdx.y * 128;
    f32x4 acc[16];
#pragma unroll
    for (int i = 0; i < 16; ++i) acc[i] = (f32x4){0.f, 0.f, 0.f, 0.f};
    kloop_pipe(Ap, 4096, Bp, 4096, 256, acc, sm);
    store_tile128(Cp, 512, acc);
}

// merged: blocks 0..511 = exclusive prefix scan over chunks of AM (memory-bound);
//         blocks 512..767 = P = tril(Q_c K_c^T) (compute-bound) -- independent, overlap.
__global__ __launch_bounds__(256, 2) void scan_phaseS(short* __restrict__ AM,
                                                      const short* __restrict__ Q,
                                                      const short* __restrict__ K,
                                                      short* __restrict__ P) {
    LDS_DECL;
    if (blockIdx.x < 512) {
        int i = blockIdx.x * 256 + threadIdx.x;   // 0..131071
        int b = i >> 15;
        int vk8 = i & 32767;
        size_t base = (size_t)b * 16 * 262144 + (size_t)vk8 * 8;
        float acc[8];
#pragma unroll
        for (int s = 0; s < 8; ++s) acc[s] = 0.f;
        for (int c = 0; c < 16; ++c) {
            short* p = AM + base + (size_t)c * 262144;
            short in8[8];
            *(int4*)in8 = *(const int4*)p;
            short out8[8];
#pragma unroll
            for (int s = 0; s < 8; ++s) out8[s] = f2bf(acc[s]);
            *(int4*)p = *(const int4*)out8;
#pragma unroll
            for (int s = 0; s < 8; ++s) acc[s] += bf2f(in8[s]);
        }
        return;
    }
    const int e = blockIdx.x - 512;               // 0..255
    const int bc = e >> 2, mt = e & 1, nt = (e >> 1) & 1;
    if (mt < nt) return;                          // dead tile (never read)
    const int b = bc >> 4, c = bc & 15;
    short* Pt = P + (size_t)bc * 65536 + (size_t)mt * 128 * 256 + nt * 128;
    const short* Ap = Q + ((size_t)(b * 4096 + c * 256 + mt * 128)) * 512;
    const short* Bp = K + ((size_t)(b * 4096 + c * 256 + nt * 128)) * 512;
    f32x4 acc[16];
#pragma unroll
    for (int i = 0; i < 16; ++i) acc[i] = (f32x4){0.f, 0.f, 0.f, 0.f};
    kloop_pipe(Ap, 512, Bp, 512, 512, acc, sm);
    const int lane = threadIdx.x & 63, wv = threadIdx.x >> 6;
    const int quad = lane >> 4, lr = lane & 15;
    const int wr = (wv >> 1) * 64, wc = (wv & 1) * 64;
    const bool diag = (mt == nt);
#pragma unroll
    for (int i = 0; i < 4; ++i)
#pragma unroll
        for (int j = 0; j < 4; ++j)
#pragma unroll
            for (int r = 0; r < 4; ++r) {
                int t = wr + i * 16 + quad * 4 + r;
                int jj = wc + j * 16 + lr;
                float v = (!diag || jj <= t) ? acc[i * 4 + j][r] : 0.f;
                Pt[(size_t)t * 256 + jj] = f2bf(v);
            }
}

// Y_c = Q_c * Mpre_c^T + tril(P_c) * V_c ; grid (2 mt, 4 nt, 64 bc)
__global__ __launch_bounds__(256, 2) void phaseY(const short* __restrict__ Q,
                                                 const short* __restrict__ Mpre,
                                                 const short* __restrict__ P,
                                                 const short* __restrict__ Vt,
                                                 short* __restrict__ Y) {
    LDS_DECL;
    const int bc = blockIdx.z, b = bc >> 4, c = bc & 15;
    const int mt = blockIdx.x, nt = blockIdx.y;
    f32x4 acc[16];
#pragma unroll
    for (int i = 0; i < 16; ++i) acc[i] = (f32x4){0.f, 0.f, 0.f, 0.f};
    // inter: Y[t][v] += sum_k Q[t][k] * Mpre[v][k]
    const short* Ai = Q + ((size_t)(b * 4096 + c * 256 + mt * 128)) * 512;
    const short* Bi = Mpre + (size_t)bc * 262144 + (size_t)nt * 128 * 512;
    kloop_pipe(Ai, 512, Bi, 512, 512, acc, sm);
    // intra: Y[t][v] += sum_j P[t][j] * Vt[v][j]; for mt=0 only j<128 nonzero
    const short* Ap = P + (size_t)bc * 65536 + (size_t)mt * 128 * 256;
    const short* Bv = Vt + ((size_t)b * 512 + nt * 128) * 4096 + c * 256;
    kloop_pipe(Ap, 256, Bv, 4096, (mt + 1) * 128, acc, sm);
    short* Cp = Y + ((size_t)(b * 4096 + c * 256 + mt * 128)) * 512 + nt * 128;
    store_tile128(Cp, 512, acc);
}

// generic C[M,N] = A . Bt^T (output projection)
template <typename OutT>
__global__ __launch_bounds__(256, 2) void gemm128(const short* __restrict__ A, int lda,
                                                  const short* __restrict__ B, int ldb,
                                                  OutT* __restrict__ C, int ldc, int Kd) {
    LDS_DECL;
    const short* At = A + (size_t)blockIdx.x * 128 * lda;
    const short* Bt = B + (size_t)blockIdx.y * 128 * ldb;
    OutT* Ct = C + (size_t)blockIdx.x * 128 * ldc + blockIdx.y * 128;
    f32x4 acc[16];
#pragma unroll
    for (int i = 0; i < 16; ++i) acc[i] = (f32x4){0.f, 0.f, 0.f, 0.f};
    kloop_pipe(At, lda, Bt, ldb, Kd, acc, sm);
    store_tile128(Ct, ldc, acc);
}

// ---------------- host ----------------

extern "C" void kernel_launch(void* const* d_in, const int* in_sizes, int n_in,
                              void* d_out, int out_size, void* d_ws, size_t ws_size,
                              hipStream_t stream) {
    const float* x  = (const float*)d_in[0];
    const float* Wq = (const float*)d_in[1];
    const float* Wk = (const float*)d_in[2];
    const float* Wv = (const float*)d_in[3];
    const float* Wo = (const float*)d_in[4];
    float* out = (float*)d_out;

    const size_t NTD = 16384 * 512;   // 8,388,608 elems

    short* ws  = (short*)d_ws;
    short* Xp  = ws;                  // 8.39M : packed X fragments
    short* Qb  = Xp + NTD;
    short* Kb  = Qb + NTD;
    short* Kt  = Kb + NTD;
    short* Vt  = Kt + NTD;
    short* P   = Vt + NTD;            // 4.19M
    short* W4T = P + 4194304;         // 1.05M : PW (packed QKV) | WoT
    short* AM  = W4T + 1048576;       // 16.78M
    short* Yb  = Kb;                  // Kb dead after scan_phaseS

    short* PW  = W4T;                 // 786432 shorts (fills old WqT|WkT|WvT slots)
    short* WoT = W4T + 786432;        // unchanged address

    prep_kernel<<<5504, 256, 0, stream>>>(x, Xp, Wq, Wk, Wv, Wo, PW, WoT);
    proj_qkv<<<256, 512, 0, stream>>>(Xp, PW, Qb, Kb, Vt, Kt);
    phaseA<<<dim3(4, 4, 64), 256, 0, stream>>>(Vt, Kt, AM);
    scan_phaseS<<<768, 256, 0, stream>>>(AM, Qb, Kb, P);
    phaseY<<<dim3(2, 4, 64), 256, 0, stream>>>(Qb, AM, P, Vt, Yb);
    gemm128<float><<<dim3(128, 4), 256, 0, stream>>>(Yb, 512, WoT, 512, out, 512, 512);
}